// Round 3
// baseline (763.837 us; speedup 1.0000x reference)
//
#include <hip/hip_runtime.h>

// Exact DTW, register-systolic wavefront, single workgroup, barrier-light.
// 256 lanes; lane p owns rows [16p, 16p+16). Lane p is skewed 1 step behind
// lane p-1 and computes a PAIR of columns (j, j+1) per step. Neighbor bottom
// values move lane-to-lane via __shfl_up (no barrier, no LDS) inside a wave;
// across the 3 wave boundaries via a small LDS ring with 64 steps of slack,
// synchronized by one __syncthreads every 32 steps.

#define N     4096
#define TPB   256
#define RPL   16              // rows per lane
#define NW    (TPB / 64)      // 4 waves
#define KS    64              // extra cross-wave slack (steps)
#define KB    32              // barrier period (steps); drift < KB < KS
#define RING  128             // ring entries (column pairs) per wave boundary
#define BIG   1e30f
// last lane start = 3*(64+KS) + 63 = 447; last active step = 447 + 2047 = 2494
#define STEPS 2496            // rounded up to multiple of KB

__global__ __launch_bounds__(TPB, 1)
void dtw_systolic(const float* __restrict__ xg, const float* __restrict__ yg,
                  float* __restrict__ out) {
    __shared__ float ylds[N];                    // 16 KB
    __shared__ float ring[NW - 1][RING * 2];     // 3 KB, (lo,hi) pairs

    const int t    = threadIdx.x;
    const int lane = t & 63;
    const int w    = t >> 6;
    const int woff = w * (64 + KS);
    const int start = woff + lane;               // first active step of this lane

    // stage y (coalesced float4)
    for (int i = t; i < N / 4; i += TPB)
        ((float4*)ylds)[i] = ((const float4*)yg)[i];
    // init rings to BIG (pre-start reads must see out-of-band)
    for (int i = t; i < (NW - 1) * RING * 2; i += TPB)
        ((float*)ring)[i] = BIG;

    float x[RPL], carry[RPL];
    #pragma unroll
    for (int r = 0; r < RPL; ++r) {
        x[r] = xg[t * RPL + r];
        carry[r] = BIG;                          // D[row][-1]
    }

    float bot_lo = BIG, bot_hi = BIG;            // my bottoms of previous pair
    float nb_prev = BIG;                         // neighbor bottom of col j-1

    __syncthreads();

    // prime prefetch registers for step 0
    float2 yc, rv = make_float2(BIG, BIG);
    {
        int jp = 2 * (0 - start);
        jp = min(max(jp, 0), N - 2);
        yc = *(const float2*)&ylds[jp];
        if (w > 0) {
            unsigned ridx = (unsigned)(0 - woff) & (RING - 1);
            rv = *(const float2*)&ring[w - 1][ridx * 2];
        }
    }

    for (int sb = 0; sb < STEPS; sb += KB) {
        for (int ss = 0; ss < KB; ++ss) {
            const int s = sb + ss;

            // ---- uniform handoff (all lanes execute) ----
            float nb_lo = __shfl_up(bot_lo, 1);  // neighbor bottom(col j)
            float nb_hi = __shfl_up(bot_hi, 1);  // neighbor bottom(col j+1)
            if (lane == 0) {                     // wave boundary: ring / edge
                nb_lo = (w == 0) ? BIG : rv.x;
                nb_hi = (w == 0) ? BIG : rv.y;
            }
            // prefetch NEXT step's ring value (uniform address per wave)
            if (w > 0) {
                unsigned ridx = (unsigned)(s + 1 - woff) & (RING - 1);
                rv = *(const float2*)&ring[w - 1][ridx * 2];
            }

            const int j = 2 * (s - start);       // my column pair base
            const float2 ycur = yc;
            // prefetch NEXT step's y pair (clamped address)
            {
                int jn = min(max(j + 2, 0), N - 2);
                yc = *(const float2*)&ylds[jn];
            }

            if ((unsigned)j < (unsigned)N) {     // active: j in {0,2,...,4094}
                // ---- column j ----
                float up = nb_lo, diag = nb_prev;
                #pragma unroll
                for (int r = 0; r < RPL; ++r) {
                    const float old = carry[r];
                    float m = fminf(up, fminf(old, diag));
                    if (r == 0) { if (t == 0 && j == 0) m = 0.0f; }  // D[0][0]=c
                    const float v = fabsf(x[r] - ycur.x) + m;
                    carry[r] = v; up = v; diag = old;
                }
                bot_lo = carry[RPL - 1];
                // ---- column j+1 ----
                up = nb_hi; diag = nb_lo;
                #pragma unroll
                for (int r = 0; r < RPL; ++r) {
                    const float old = carry[r];
                    const float m = fminf(up, fminf(old, diag));
                    const float v = fabsf(x[r] - ycur.y) + m;
                    carry[r] = v; up = v; diag = old;
                }
                bot_hi = carry[RPL - 1];
                nb_prev = nb_hi;

                // export across wave boundary (bottom lane of waves 0..2)
                if (lane == 63 && w < NW - 1) {
                    unsigned widx = (unsigned)(s - woff - 63) & (RING - 1);
                    *(float2*)&ring[w][widx * 2] = make_float2(bot_lo, bot_hi);
                }
            }
        }
        __syncthreads();   // bounds cross-wave drift to < KB; publishes ring
    }

    // D[N-1][N-1]: last lane, last row
    if (t == TPB - 1) out[0] = carry[RPL - 1];
}

extern "C" void kernel_launch(void* const* d_in, const int* in_sizes, int n_in,
                              void* d_out, int out_size, void* d_ws, size_t ws_size,
                              hipStream_t stream) {
    const float* src = (const float*)d_in[0];
    const float* tgt = (const float*)d_in[1];
    float* out = (float*)d_out;
    hipLaunchKernelGGL(dtw_systolic, dim3(1), dim3(TPB), 0, stream, src, tgt, out);
}

// Round 4
// 687.976 us; speedup vs baseline: 1.1103x; 1.1103x over previous
//
#include <hip/hip_runtime.h>

// Exact DTW, 4-CU row-split pipelined DP.
// WG g owns rows [1024g, 1024g+1024); 256 threads x R=4 rows; columns in
// chunks of C=4. Within a WG: R2's tile wavefront (thread t runs chunk c at
// local step s = t + c; LDS double-buffered bottom-row handoff; one barrier
// per step). Across WGs: thread 255 streams its bottom-row chunks to a global
// buffer, release-flag every BCH=16 chunks; consumer WG's wave 0 spins on the
// flag and block-loads 64 floats into an LDS ring one block ahead. The spin
// self-establishes ~290 steps of lead, so steady-state handoff is one
// amortized L2/L3 read per 16 steps, off the critical path.

#define N      4096
#define TPB    256
#define C      4
#define NCH    (N / C)          // 1024 chunks
#define BCH    16               // chunks per cross-WG handoff block (64 floats)
#define NBLK   (NCH / BCH)      // 64 blocks
#define BIG    1e30f
// y staged with 16B pad per 32 floats: keeps float4 loads aligned, spreads banks
#define YIDX(j) ((j) + (((j) >> 5) << 2))

template <int G, int R>
__global__ __launch_bounds__(TPB, 1)
void dtw_pipe(const float* __restrict__ xg, const float* __restrict__ yg,
              float* __restrict__ out, float* __restrict__ gbuf,
              int* __restrict__ flags) {
    __shared__ float ylds[N + (N >> 5) * 4];     // 18 KB
    __shared__ float bot[2][TPB][C + 1];         // 10 KB, stride 5 (coprime 32)
    __shared__ float nbring[2][BCH * C];         // 512 B cross-WG ring

    const int t = threadIdx.x;
    const int g = blockIdx.x;
    const int LSTEPS = TPB + NCH - 1;            // 1279

    for (int j4 = t * 4; j4 < N; j4 += TPB * 4) {
        const float4 v = *(const float4*)&yg[j4];
        *(float4*)&ylds[YIDX(j4)] = v;           // j4%32 in {0..28}: no pad crossing
    }

    float x[R], carry[R];
    const int i0 = g * (N / G) + t * R;
#pragma unroll
    for (int r = 0; r < R; ++r) { x[r] = xg[i0 + r]; carry[r] = BIG; }

    // diag carry D[i0-1][j0-1] at left edge of current chunk.
    // (0,0) trick: min(BIG, min(BIG, 0)) = 0 reproduces D[0][0] = c[0][0].
    float diagc = (g == 0 && t == 0) ? 0.0f : BIG;

    // prologue: fetch neighbor block 0 into ring slot 0
    if (G > 1 && g > 0 && t < BCH * C) {
        while (__hip_atomic_load(&flags[(g - 1) * NBLK], __ATOMIC_ACQUIRE,
                                 __HIP_MEMORY_SCOPE_AGENT) == 0) {}
        nbring[0][t] = gbuf[(size_t)(g - 1) * N + t];
    }
    __syncthreads();

    for (int s = 0; s < LSTEPS; ++s) {
        // wave 0 of consumer WGs: prefetch neighbor block s/BCH+1 (slot parity flips)
        if (G > 1 && g > 0 && t < BCH * C && (s & (BCH - 1)) == 0) {
            const int b2 = s / BCH + 1;
            if (b2 < NBLK) {
                while (__hip_atomic_load(&flags[(g - 1) * NBLK + b2], __ATOMIC_ACQUIRE,
                                         __HIP_MEMORY_SCOPE_AGENT) == 0) {}
                nbring[b2 & 1][t] = gbuf[(size_t)(g - 1) * N + b2 * (BCH * C) + t];
            }
        }

        const int c = s - t;
        if (0 <= c && c < NCH) {
            const int rb = (s + 1) & 1, wb = s & 1;
            float nb0, nb1, nb2, nb3;            // neighbor bottoms, cols j0..j0+3
            if (t > 0) {
                const float* bp = bot[rb][t - 1];
                nb0 = bp[0]; nb1 = bp[1]; nb2 = bp[2]; nb3 = bp[3];
            } else if (G > 1 && g > 0) {
                const float* nr = &nbring[(c / BCH) & 1][(c & (BCH - 1)) * C];
                nb0 = nr[0]; nb1 = nr[1]; nb2 = nr[2]; nb3 = nr[3];
            } else {
                nb0 = nb1 = nb2 = nb3 = BIG;
            }
            const int j0 = c * C;
            const float4 yv = *(const float4*)&ylds[YIDX(j0)];

            float bt0, bt1, bt2, bt3;
#define DO_COL(YC, NB, DG, BT)                                            \
            { float up = (NB), dgv = (DG);                                \
              _Pragma("unroll")                                           \
              for (int r = 0; r < R; ++r) {                               \
                  const float old = carry[r];                             \
                  const float v = fabsf(x[r] - (YC)) +                    \
                                  fminf(up, fminf(old, dgv));             \
                  carry[r] = v; up = v; dgv = old;                        \
              }                                                           \
              (BT) = up; }
            DO_COL(yv.x, nb0, diagc, bt0)
            DO_COL(yv.y, nb1, nb0,   bt1)
            DO_COL(yv.z, nb2, nb1,   bt2)
            DO_COL(yv.w, nb3, nb2,   bt3)
#undef DO_COL
            diagc = nb3;

            float* bw = bot[wb][t];
            bw[0] = bt0; bw[1] = bt1; bw[2] = bt2; bw[3] = bt3;

            // producer edge: stream bottom chunk to global, flag every BCH chunks
            if (G > 1 && g < G - 1 && t == TPB - 1) {
                *(float4*)&gbuf[(size_t)g * N + j0] = make_float4(bt0, bt1, bt2, bt3);
                if ((c & (BCH - 1)) == BCH - 1)
                    __hip_atomic_store(&flags[g * NBLK + c / BCH], 1,
                                       __ATOMIC_RELEASE, __HIP_MEMORY_SCOPE_AGENT);
            }
        }
        __syncthreads();
    }

    if (g == G - 1 && t == TPB - 1) out[0] = carry[R - 1];
}

extern "C" void kernel_launch(void* const* d_in, const int* in_sizes, int n_in,
                              void* d_out, int out_size, void* d_ws, size_t ws_size,
                              hipStream_t stream) {
    const float* src = (const float*)d_in[0];
    const float* tgt = (const float*)d_in[1];
    float* out = (float*)d_out;

    const size_t req = 4096 + 3 * (size_t)N * sizeof(float);   // flags + 3 boundary buffers
    if (ws_size >= req) {
        int*   flags = (int*)d_ws;
        float* gbuf  = (float*)((char*)d_ws + 4096);
        hipMemsetAsync(d_ws, 0, 4096, stream);                 // clean flags every call
        hipLaunchKernelGGL((dtw_pipe<4, 4>), dim3(4), dim3(TPB), 0, stream,
                           src, tgt, out, gbuf, flags);
    } else {
        // fallback: single-WG variant (16 rows/thread), no cross-WG traffic
        hipLaunchKernelGGL((dtw_pipe<1, 16>), dim3(1), dim3(TPB), 0, stream,
                           src, tgt, out, (float*)nullptr, (int*)nullptr);
    }
}